// Round 4
// baseline (152.074 us; speedup 1.0000x reference)
//
#include <hip/hip_runtime.h>
#include <hip/hip_fp16.h>
#include <math.h>

#define DET 512
#define NA 180
#define NTILES 2048                   // 32 (x) x 64 (y) tiles of 16x8 pixels
#define TANG_FLOATS (NTILES * NA * 4) // 5.9 MB
#define CHUNK 45
#define WWIN 24

// ws layout (floats): [0, TANG_FLOATS) tang; then xsT packed half2 [a][d][b4] (1.47 MB)

// ---------------- prep: per-(tile,angle) constants ----------------
__global__ __launch_bounds__(256) void prep_kernel(float4* __restrict__ tang) {
    int idx = blockIdx.x * 256 + threadIdx.x;
    if (idx >= NTILES * NA) return;
    int tile = idx / NA;
    int a = idx - tile * NA;
    float th = (float)a * 0.017453292519943295f;
    float C = 255.5f * cosf(th);
    float S = 255.5f * sinf(th);
    int x0 = (tile & 31) << 4, y0 = (tile >> 5) << 3;
    float xga = (float)(2 * x0 - 511)        * (1.0f / 511.0f);
    float xgb = (float)(2 * (x0 + 15) - 511) * (1.0f / 511.0f);
    float yga = (float)(2 * y0 - 511)        * (1.0f / 511.0f);
    float ygb = (float)(2 * (y0 + 7) - 511)  * (1.0f / 511.0f);
    // min over tile corners of yv = 255.5 + xg*C - yg*S (linear in xg,yg)
    float mn = 255.5f + fminf(xga * C, xgb * C) + fminf(-yga * S, -ygb * S);
    int w0 = (int)floorf(mn) - 1;     // -1 slack for fma rounding differences
    tang[idx] = make_float4(255.5f - (float)w0, C, S, __int_as_float(w0));
}

// ---------------- filter: one wave = full 512-tap conv of one batch-column ----------------
// grid = 180 angles x 2 batch-halves; block 256 = 4 waves; wave w -> batch 4z+w.
// lane: 8 consecutive outputs (d0 = 8*lane); taps in a 16-float register window sliding by 8.
__global__ __launch_bounds__(256) void filter_kernel(const float* __restrict__ x,
                                                     unsigned* __restrict__ xsT) {
    __shared__ float xcols[4][DET];   // 8 KB
    __shared__ float g2s[1024];       // 4 KB  g2s[i] = g(|i-512|)
    __shared__ float part[4][DET];    // 8 KB

    const int a = blockIdx.x >> 1;
    const int z = blockIdx.x & 1;
    const int t = threadIdx.x;

    for (int i = t; i < 1024; i += 256) {
        int k = i - 512; if (k < 0) k = -k;
        float g = 0.0f;
        if (k == 0)      g = 0.5f;
        else if (k & 1)  { float fk = (float)k; g = -0.20264236728467558f / (fk * fk); }
        g2s[i] = g;
    }
    for (int i = t; i < 4 * DET; i += 256) {
        int b = i >> 9, j = i & 511;
        xcols[b][j] = x[((4 * z + b) * DET + j) * NA + a];
    }
    __syncthreads();

    const int w  = t >> 6, l = t & 63;
    const int d0 = l << 3;

    float acc[8];
#pragma unroll
    for (int r = 0; r < 8; ++r) acc[r] = 0.0f;

    // W[i] = g2s[504 + d0 - j0 + i]; FMA tap index 8 + r - jj in [1,15]
    float W[16];
#pragma unroll
    for (int q = 0; q < 4; ++q)
        *(float4*)(W + 4 * q) = *(const float4*)(g2s + 504 + d0 + 4 * q);
    float xv[8];
    *(float4*)(xv)     = *(const float4*)(&xcols[w][0]);
    *(float4*)(xv + 4) = *(const float4*)(&xcols[w][4]);

    for (int j0 = 0; j0 < 512; j0 += 8) {
        float nxv[8], nW[8];
        const bool more = (j0 < 504);
        if (more) {
            *(float4*)(nxv)     = *(const float4*)(&xcols[w][j0 + 8]);
            *(float4*)(nxv + 4) = *(const float4*)(&xcols[w][j0 + 12]);
            *(float4*)(nW)      = *(const float4*)(g2s + 496 + d0 - j0);
            *(float4*)(nW + 4)  = *(const float4*)(g2s + 500 + d0 - j0);
        }
#pragma unroll
        for (int jj = 0; jj < 8; ++jj)
#pragma unroll
            for (int r = 0; r < 8; ++r)
                acc[r] = fmaf(xv[jj], W[8 + r - jj], acc[r]);
        if (more) {
#pragma unroll
            for (int i = 7; i >= 0; --i) W[i + 8] = W[i];
#pragma unroll
            for (int i = 0; i < 8; ++i) { W[i] = nW[i]; xv[i] = nxv[i]; }
        }
    }

    *(float4*)(&part[w][d0])     = *(const float4*)(acc);
    *(float4*)(&part[w][d0 + 4]) = *(const float4*)(acc + 4);
    __syncthreads();

    // pack this block's 4 batches into 2 adjacent half2 words per d: uint2 store
    for (int i = t; i < DET; i += 256) {
        __half2 h0 = __halves2half2(__float2half_rn(part[0][i]), __float2half_rn(part[1][i]));
        __half2 h1 = __halves2half2(__float2half_rn(part[2][i]), __float2half_rn(part[3][i]));
        uint2 pk = make_uint2(*(unsigned*)&h0, *(unsigned*)&h1);
        *(uint2*)(xsT + ((size_t)a * DET + i) * 4 + 2 * z) = pk;
    }
}

// ---------------- backprojection: 16x8 tiles, 4 batches/thread, 32 waves/CU ----------------
// block 256 = 128 pixels x 2 batch-groups (g = t>>7, wave-uniform).
// win2[ci][g][d] = uint2 {half2(b0,b1), half2(b2,b3)} for group g at window cell d.
// Per pixel-angle: one adjacent uint2 pair read (ds_read2_b64-shaped, 16 B/lane).
__global__ __launch_bounds__(256, 8) void backproj_kernel(const float4* __restrict__ tang,
                                                          const unsigned* __restrict__ xsT,
                                                          float* __restrict__ out) {
    __shared__ uint2 win2[CHUNK][2][WWIN];   // 17.3 KB

    const int tile = blockIdx.x;
    const int x0 = (tile & 31) << 4, y0 = (tile >> 5) << 3;
    const int t = threadIdx.x;
    const int p = t & 127;
    const int g = t >> 7;
    const int px = p & 15, py = p >> 4;
    const float xg = (float)(2 * (x0 + px) - 511) * (1.0f / 511.0f);
    const float yg = (float)(2 * (y0 + py) - 511) * (1.0f / 511.0f);

    float acc[4] = {0.0f, 0.0f, 0.0f, 0.0f};

    const float4* ta = tang + (size_t)tile * NA;
    const uint4*  xs4 = (const uint4*)xsT;

    for (int c = 0; c < NA / CHUNK; ++c) {
        __syncthreads();   // previous chunk's readers done
        // stage CHUNK windows: one uint4 (8 batches) per cell -> two uint2 groups
        for (int i = t; i < CHUNK * WWIN; i += 256) {
            int ci  = i / WWIN;
            int off = i - ci * WWIN;
            int a   = c * CHUNK + ci;
            int d   = __float_as_int(ta[a].w) + off;
            uint4 v = make_uint4(0u, 0u, 0u, 0u);
            if ((unsigned)d < 512u)
                v = xs4[(size_t)a * DET + d];
            win2[ci][0][off] = make_uint2(v.x, v.y);
            win2[ci][1][off] = make_uint2(v.z, v.w);
        }
        __syncthreads();

#pragma unroll 5
        for (int ci = 0; ci < CHUNK; ++ci) {
            float4 A = ta[c * CHUNK + ci];          // uniform -> s_load_dwordx4
            float yv = fmaf(xg, A.y, A.x) - yg * A.z;  // window-relative position
            float fi = floorf(yv);
            int  off = (int)fi;
            __half2 w2 = __float2half2_rn(yv - fi);
            const uint2* wp = &win2[ci][g][0];
            uint2 u0 = wp[off];
            uint2 u1 = wp[off + 1];
            __half2 p0 = *(__half2*)&u0.x, p1 = *(__half2*)&u0.y;
            __half2 q0 = *(__half2*)&u1.x, q1 = *(__half2*)&u1.y;
            __half2 r0 = __hfma2(w2, __hsub2(q0, p0), p0);
            __half2 r1 = __hfma2(w2, __hsub2(q1, p1), p1);
            float2 f0 = __half22float2(r0);
            float2 f1 = __half22float2(r1);
            acc[0] += f0.x; acc[1] += f0.y; acc[2] += f1.x; acc[3] += f1.y;
        }
    }

    const float r2 = xg * xg + yg * yg;
    const float m  = (r2 <= 1.0f) ? 0.008726646259971648f : 0.0f;  // pi/360 masked
    const size_t pbase = ((size_t)(y0 + py) << 9) + (size_t)(x0 + px);
#pragma unroll
    for (int j = 0; j < 4; ++j)
        out[((size_t)(4 * g + j) << 18) + pbase] = acc[j] * m;
}

extern "C" void kernel_launch(void* const* d_in, const int* in_sizes, int n_in,
                              void* d_out, int out_size, void* d_ws, size_t ws_size,
                              hipStream_t stream) {
    const float* x = (const float*)d_in[0];
    float* out = (float*)d_out;
    float* ws  = (float*)d_ws;

    float4*   tang = (float4*)ws;
    unsigned* xsT  = (unsigned*)(ws + TANG_FLOATS);

    prep_kernel<<<(NTILES * NA + 255) / 256, 256, 0, stream>>>(tang);
    filter_kernel<<<2 * NA, 256, 0, stream>>>(x, xsT);
    backproj_kernel<<<NTILES, 256, 0, stream>>>(tang, xsT, out);
}

// Round 6
// 144.668 us; speedup vs baseline: 1.0512x; 1.0512x over previous
//
#include <hip/hip_runtime.h>
#include <hip/hip_fp16.h>
#include <math.h>

#define DET 512
#define NA 180
#define NTILES 2048                   // 32 (x) x 64 (y) tiles of 16x8 pixels
#define TANG_FLOATS (NTILES * NA * 4) // 5.9 MB
#define CHUNK 20
#define WWIN 24

typedef _Float16 half2_t __attribute__((ext_vector_type(2)));

// ws layout (floats):
//  [0, TANG_FLOATS)  : tang float4 per (tile,angle): {bias=255.5-w0, C, S, w0 int bits}
//  then xsT2         : uint4[NA*DET*2] tap-pair-packed sinogram (2.95 MB):
//                      uint4 (a,d,g) = { half2(s_b[d], s_b[d+1]) : b = 4g..4g+3 }

// ---------------- fused prep + filter ----------------
// blocks [0, 2*NA): filter (angle = blk>>1, batch-half z = blk&1, 4 batches)
// blocks [2*NA, 2*NA+1440): prep of tang
__global__ __launch_bounds__(256) void prep_filter_kernel(const float* __restrict__ x,
                                                          float4* __restrict__ tang,
                                                          uint4* __restrict__ xsT2) {
    const int t = threadIdx.x;
    if (blockIdx.x >= 2 * NA) {
        int idx = (blockIdx.x - 2 * NA) * 256 + t;
        if (idx < NTILES * NA) {
            int tile = idx / NA;
            int a = idx - tile * NA;
            float th = (float)a * 0.017453292519943295f;
            float C = 255.5f * cosf(th);
            float S = 255.5f * sinf(th);
            int x0 = (tile & 31) << 4, y0 = (tile >> 5) << 3;
            float xga = (float)(2 * x0 - 511)        * (1.0f / 511.0f);
            float xgb = (float)(2 * (x0 + 15) - 511) * (1.0f / 511.0f);
            float yga = (float)(2 * y0 - 511)        * (1.0f / 511.0f);
            float ygb = (float)(2 * (y0 + 7) - 511)  * (1.0f / 511.0f);
            // min over tile corners of yv = 255.5 + xg*C - yg*S (linear in xg,yg)
            float mn = 255.5f + fminf(xga * C, xgb * C) + fminf(-yga * S, -ygb * S);
            int w0 = (int)floorf(mn) - 1;     // -1 slack for fma rounding differences
            tang[idx] = make_float4(255.5f - (float)w0, C, S, __int_as_float(w0));
        }
        return;
    }

    // ---- filter: one wave = full 512-tap conv of one batch-column ----
    __shared__ float xcols[4][DET];   // 8 KB
    __shared__ float g2s[1024];       // 4 KB  g2s[i] = g(|i-512|)
    __shared__ float part[4][DET];    // 8 KB

    const int a = blockIdx.x >> 1;
    const int z = blockIdx.x & 1;

    for (int i = t; i < 1024; i += 256) {
        int k = i - 512; if (k < 0) k = -k;
        float g = 0.0f;
        if (k == 0)      g = 0.5f;
        else if (k & 1)  { float fk = (float)k; g = -0.20264236728467558f / (fk * fk); }
        g2s[i] = g;
    }
    for (int i = t; i < 4 * DET; i += 256) {
        int b = i >> 9, j = i & 511;
        xcols[b][j] = x[((4 * z + b) * DET + j) * NA + a];
    }
    __syncthreads();

    const int w  = t >> 6, l = t & 63;
    const int d0 = l << 3;

    float acc[8];
#pragma unroll
    for (int r = 0; r < 8; ++r) acc[r] = 0.0f;

    float W[16];
#pragma unroll
    for (int q = 0; q < 4; ++q)
        *(float4*)(W + 4 * q) = *(const float4*)(g2s + 504 + d0 + 4 * q);
    float xv[8];
    *(float4*)(xv)     = *(const float4*)(&xcols[w][0]);
    *(float4*)(xv + 4) = *(const float4*)(&xcols[w][4]);

    for (int j0 = 0; j0 < 512; j0 += 8) {
        float nxv[8], nW[8];
        const bool more = (j0 < 504);
        if (more) {
            *(float4*)(nxv)     = *(const float4*)(&xcols[w][j0 + 8]);
            *(float4*)(nxv + 4) = *(const float4*)(&xcols[w][j0 + 12]);
            *(float4*)(nW)      = *(const float4*)(g2s + 496 + d0 - j0);
            *(float4*)(nW + 4)  = *(const float4*)(g2s + 500 + d0 - j0);
        }
#pragma unroll
        for (int jj = 0; jj < 8; ++jj)
#pragma unroll
            for (int r = 0; r < 8; ++r)
                acc[r] = fmaf(xv[jj], W[8 + r - jj], acc[r]);
        if (more) {
#pragma unroll
            for (int i = 7; i >= 0; --i) W[i + 8] = W[i];
#pragma unroll
            for (int i = 0; i < 8; ++i) { W[i] = nW[i]; xv[i] = nxv[i]; }
        }
    }

    *(float4*)(&part[w][d0])     = *(const float4*)(acc);
    *(float4*)(&part[w][d0 + 4]) = *(const float4*)(acc + 4);
    __syncthreads();

    // tap-pair pack: word b = half2(part[b][i], part[b][i+1]); d=511 pairs with 0
    for (int i = t; i < DET; i += 256) {
        uint4 pk;
        unsigned* pkw = &pk.x;
#pragma unroll
        for (int b = 0; b < 4; ++b) {
            float v0 = part[b][i];
            float v1 = (i < DET - 1) ? part[b][i + 1] : 0.0f;
            __half2 h = __halves2half2(__float2half_rn(v0), __float2half_rn(v1));
            pkw[b] = *(unsigned*)&h;
        }
        xsT2[((size_t)a * DET + i) * 2 + z] = pk;
    }
}

// ---------------- backprojection: tap-pair windows, one b128 + 4 dot2 per iter ----------------
// block 256 = 128 pixels (16x8 tile) x 2 batch-groups (g = t>>7, wave-uniform).
__global__ __launch_bounds__(256, 8) void backproj_kernel(const float4* __restrict__ tang,
                                                          const uint4* __restrict__ xs,
                                                          float* __restrict__ out) {
    __shared__ uint4 win[CHUNK][WWIN][2];   // 15.36 KB

    const int tile = blockIdx.x;
    const int x0 = (tile & 31) << 4, y0 = (tile >> 5) << 3;
    const int t = threadIdx.x;
    const int p = t & 127;
    const int g = t >> 7;
    const int px = p & 15, py = p >> 4;
    const float xg = (float)(2 * (x0 + px) - 511) * (1.0f / 511.0f);
    const float yg = (float)(2 * (y0 + py) - 511) * (1.0f / 511.0f);

    float acc[4] = {0.0f, 0.0f, 0.0f, 0.0f};

    const float4* ta = tang + (size_t)tile * NA;

    for (int c = 0; c < NA / CHUNK; ++c) {
        __syncthreads();   // previous chunk's readers done
        // stage CHUNK windows: CHUNK*WWIN*2 uint4s, coalesced (g,off fastest)
        for (int i = t; i < CHUNK * WWIN * 2; i += 256) {
            int ci  = i / (WWIN * 2);
            int r   = i - ci * (WWIN * 2);
            int off = r >> 1, gg = r & 1;
            int a   = c * CHUNK + ci;
            int d   = __float_as_int(ta[a].w) + off;
            uint4 v = make_uint4(0u, 0u, 0u, 0u);
            if ((unsigned)d < 512u)
                v = xs[((size_t)a * DET + d) * 2 + gg];
            win[ci][off][gg] = v;
        }
        __syncthreads();

#pragma unroll 5
        for (int ci = 0; ci < CHUNK; ++ci) {
            float4 A = ta[c * CHUNK + ci];             // uniform -> s_load_dwordx4
            float yv = fmaf(xg, A.y, A.x) - yg * A.z;  // window-relative, >= 1
            float fi = floorf(yv);
            int  off = (int)fi;
            float wgt = yv - fi;
            auto pkw = __builtin_amdgcn_cvt_pkrtz(1.0f - wgt, wgt);  // v_cvt_pkrtz_f16_f32
            half2_t wv = *(half2_t*)&pkw;
            uint4 u = win[ci][off][g];                 // one ds_read_b128
            acc[0] = __builtin_amdgcn_fdot2(*(half2_t*)&u.x, wv, acc[0], false);
            acc[1] = __builtin_amdgcn_fdot2(*(half2_t*)&u.y, wv, acc[1], false);
            acc[2] = __builtin_amdgcn_fdot2(*(half2_t*)&u.z, wv, acc[2], false);
            acc[3] = __builtin_amdgcn_fdot2(*(half2_t*)&u.w, wv, acc[3], false);
        }
    }

    const float r2 = xg * xg + yg * yg;
    const float m  = (r2 <= 1.0f) ? 0.008726646259971648f : 0.0f;  // pi/360 masked
    const size_t pbase = ((size_t)(y0 + py) << 9) + (size_t)(x0 + px);
#pragma unroll
    for (int j = 0; j < 4; ++j)
        out[((size_t)(4 * g + j) << 18) + pbase] = acc[j] * m;
}

extern "C" void kernel_launch(void* const* d_in, const int* in_sizes, int n_in,
                              void* d_out, int out_size, void* d_ws, size_t ws_size,
                              hipStream_t stream) {
    const float* x = (const float*)d_in[0];
    float* out = (float*)d_out;
    float* ws  = (float*)d_ws;

    float4* tang = (float4*)ws;
    uint4*  xsT2 = (uint4*)(ws + TANG_FLOATS);

    const int prep_blocks = (NTILES * NA + 255) / 256;   // 1440
    prep_filter_kernel<<<2 * NA + prep_blocks, 256, 0, stream>>>(x, tang, xsT2);
    backproj_kernel<<<NTILES, 256, 0, stream>>>(tang, xsT2, out);
}

// Round 7
// 130.591 us; speedup vs baseline: 1.1645x; 1.1078x over previous
//
#include <hip/hip_runtime.h>
#include <hip/hip_fp16.h>
#include <math.h>

#define DET 512
#define NA 180
#define NTILES 1024                   // 32 x 32 tiles of 16x16 pixels
#define TANG_FLOATS (NTILES * NA * 4) // 2.95 MB
#define CHUNK 36
#define WWIN 24

typedef _Float16 half2_t __attribute__((ext_vector_type(2)));

// ws layout (floats):
//  [0, TANG_FLOATS)  : tang float4 per (tile,angle): {bias=255.5-w0, C, S, w0 int bits}
//  then xsT2         : uint4[NA*DET*2] tap-pair-packed sinogram (2.95 MB):
//                      uint4 (a,d,g) = { half2(s_b[d], s_b[d+1]) : b = 4g..4g+3 }

// ---------------- fused prep + filter ----------------
// blocks [0, 2*NA): filter (angle = blk>>1, batch-half z = blk&1, 4 batches)
// blocks [2*NA, 2*NA+720): prep of tang
__global__ __launch_bounds__(256) void prep_filter_kernel(const float* __restrict__ x,
                                                          float4* __restrict__ tang,
                                                          uint4* __restrict__ xsT2) {
    const int t = threadIdx.x;
    if (blockIdx.x >= 2 * NA) {
        int idx = (blockIdx.x - 2 * NA) * 256 + t;
        if (idx < NTILES * NA) {
            int tile = idx / NA;
            int a = idx - tile * NA;
            float th = (float)a * 0.017453292519943295f;
            float C = 255.5f * cosf(th);
            float S = 255.5f * sinf(th);
            int x0 = (tile & 31) << 4, y0 = (tile >> 5) << 4;
            float xga = (float)(2 * x0 - 511)        * (1.0f / 511.0f);
            float xgb = (float)(2 * (x0 + 15) - 511) * (1.0f / 511.0f);
            float yga = (float)(2 * y0 - 511)        * (1.0f / 511.0f);
            float ygb = (float)(2 * (y0 + 15) - 511) * (1.0f / 511.0f);
            // min over tile corners of yv = 255.5 + xg*C - yg*S (linear in xg,yg)
            float mn = 255.5f + fminf(xga * C, xgb * C) + fminf(-yga * S, -ygb * S);
            int w0 = (int)floorf(mn) - 1;     // -1 slack for fma rounding differences
            tang[idx] = make_float4(255.5f - (float)w0, C, S, __int_as_float(w0));
        }
        return;
    }

    // ---- filter: one wave = full 512-tap conv of one batch-column ----
    __shared__ float xcols[4][DET];   // 8 KB
    __shared__ float g2s[1024];       // 4 KB  g2s[i] = g(|i-512|)
    __shared__ float part[4][DET];    // 8 KB

    const int a = blockIdx.x >> 1;
    const int z = blockIdx.x & 1;

    for (int i = t; i < 1024; i += 256) {
        int k = i - 512; if (k < 0) k = -k;
        float g = 0.0f;
        if (k == 0)      g = 0.5f;
        else if (k & 1)  { float fk = (float)k; g = -0.20264236728467558f / (fk * fk); }
        g2s[i] = g;
    }
    for (int i = t; i < 4 * DET; i += 256) {
        int b = i >> 9, j = i & 511;
        xcols[b][j] = x[((4 * z + b) * DET + j) * NA + a];
    }
    __syncthreads();

    const int w  = t >> 6, l = t & 63;
    const int d0 = l << 3;

    float acc[8];
#pragma unroll
    for (int r = 0; r < 8; ++r) acc[r] = 0.0f;

    float W[16];
#pragma unroll
    for (int q = 0; q < 4; ++q)
        *(float4*)(W + 4 * q) = *(const float4*)(g2s + 504 + d0 + 4 * q);
    float xv[8];
    *(float4*)(xv)     = *(const float4*)(&xcols[w][0]);
    *(float4*)(xv + 4) = *(const float4*)(&xcols[w][4]);

    for (int j0 = 0; j0 < 512; j0 += 8) {
        float nxv[8], nW[8];
        const bool more = (j0 < 504);
        if (more) {
            *(float4*)(nxv)     = *(const float4*)(&xcols[w][j0 + 8]);
            *(float4*)(nxv + 4) = *(const float4*)(&xcols[w][j0 + 12]);
            *(float4*)(nW)      = *(const float4*)(g2s + 496 + d0 - j0);
            *(float4*)(nW + 4)  = *(const float4*)(g2s + 500 + d0 - j0);
        }
#pragma unroll
        for (int jj = 0; jj < 8; ++jj)
#pragma unroll
            for (int r = 0; r < 8; ++r)
                acc[r] = fmaf(xv[jj], W[8 + r - jj], acc[r]);
        if (more) {
#pragma unroll
            for (int i = 7; i >= 0; --i) W[i + 8] = W[i];
#pragma unroll
            for (int i = 0; i < 8; ++i) { W[i] = nW[i]; xv[i] = nxv[i]; }
        }
    }

    *(float4*)(&part[w][d0])     = *(const float4*)(acc);
    *(float4*)(&part[w][d0 + 4]) = *(const float4*)(acc + 4);
    __syncthreads();

    // tap-pair pack: word b = half2(part[b][i], part[b][i+1]); d=511 pairs with 0
    for (int i = t; i < DET; i += 256) {
        uint4 pk;
        unsigned* pkw = &pk.x;
#pragma unroll
        for (int b = 0; b < 4; ++b) {
            float v0 = part[b][i];
            float v1 = (i < DET - 1) ? part[b][i + 1] : 0.0f;
            __half2 h = __halves2half2(__float2half_rn(v0), __float2half_rn(v1));
            pkw[b] = *(unsigned*)&h;
        }
        xsT2[((size_t)a * DET + i) * 2 + z] = pk;
    }
}

// ---------------- backprojection: 1 thread = 1 pixel x 8 batches ----------------
// block 256 = 16x16 pixel tile; per pixel-angle: addr math ONCE, 2 x ds_read_b128
// (group arrays split -> off stride 16 B -> ~2-way bank aliasing = free), 8 x v_dot2.
__global__ __launch_bounds__(256, 4) void backproj_kernel(const float4* __restrict__ tang,
                                                          const uint4* __restrict__ xs,
                                                          float* __restrict__ out) {
    __shared__ uint4 win[2][CHUNK][WWIN];   // 27.6 KB -> 4 blocks/CU

    const int tile = blockIdx.x;
    const int x0 = (tile & 31) << 4, y0 = (tile >> 5) << 4;
    const int t = threadIdx.x;
    const int px = t & 15, py = t >> 4;
    const float xg = (float)(2 * (x0 + px) - 511) * (1.0f / 511.0f);
    const float yg = (float)(2 * (y0 + py) - 511) * (1.0f / 511.0f);

    float acc[8];
#pragma unroll
    for (int j = 0; j < 8; ++j) acc[j] = 0.0f;

    const float4* ta = tang + (size_t)tile * NA;

    for (int c = 0; c < NA / CHUNK; ++c) {
        __syncthreads();   // previous chunk's readers done
        // stage CHUNK windows: CHUNK*WWIN*2 uint4s, coalesced (off,gg fastest)
        for (int i = t; i < CHUNK * WWIN * 2; i += 256) {
            int ci  = i / (WWIN * 2);
            int r   = i - ci * (WWIN * 2);
            int off = r >> 1, gg = r & 1;
            int a   = c * CHUNK + ci;
            int d   = __float_as_int(ta[a].w) + off;
            uint4 v = make_uint4(0u, 0u, 0u, 0u);
            if ((unsigned)d < 512u)
                v = xs[((size_t)a * DET + d) * 2 + gg];
            win[gg][ci][off] = v;
        }
        __syncthreads();

#pragma unroll 6
        for (int ci = 0; ci < CHUNK; ++ci) {
            float4 A = ta[c * CHUNK + ci];             // uniform -> s_load_dwordx4
            float yv = fmaf(xg, A.y, A.x) - yg * A.z;  // window-relative, >= 1
            float fi = floorf(yv);
            int  off = (int)fi;
            float wgt = yv - fi;
            auto pkw = __builtin_amdgcn_cvt_pkrtz(1.0f - wgt, wgt);  // v_cvt_pkrtz_f16_f32
            half2_t wv = *(half2_t*)&pkw;
            uint4 u0 = win[0][ci][off];                // ds_read_b128
            uint4 u1 = win[1][ci][off];                // ds_read_b128, +13824 imm offset
            acc[0] = __builtin_amdgcn_fdot2(*(half2_t*)&u0.x, wv, acc[0], false);
            acc[1] = __builtin_amdgcn_fdot2(*(half2_t*)&u0.y, wv, acc[1], false);
            acc[2] = __builtin_amdgcn_fdot2(*(half2_t*)&u0.z, wv, acc[2], false);
            acc[3] = __builtin_amdgcn_fdot2(*(half2_t*)&u0.w, wv, acc[3], false);
            acc[4] = __builtin_amdgcn_fdot2(*(half2_t*)&u1.x, wv, acc[4], false);
            acc[5] = __builtin_amdgcn_fdot2(*(half2_t*)&u1.y, wv, acc[5], false);
            acc[6] = __builtin_amdgcn_fdot2(*(half2_t*)&u1.z, wv, acc[6], false);
            acc[7] = __builtin_amdgcn_fdot2(*(half2_t*)&u1.w, wv, acc[7], false);
        }
    }

    const float r2 = xg * xg + yg * yg;
    const float m  = (r2 <= 1.0f) ? 0.008726646259971648f : 0.0f;  // pi/360 masked
    const size_t pbase = ((size_t)(y0 + py) << 9) + (size_t)(x0 + px);
#pragma unroll
    for (int j = 0; j < 8; ++j)
        out[((size_t)j << 18) + pbase] = acc[j] * m;
}

extern "C" void kernel_launch(void* const* d_in, const int* in_sizes, int n_in,
                              void* d_out, int out_size, void* d_ws, size_t ws_size,
                              hipStream_t stream) {
    const float* x = (const float*)d_in[0];
    float* out = (float*)d_out;
    float* ws  = (float*)d_ws;

    float4* tang = (float4*)ws;
    uint4*  xsT2 = (uint4*)(ws + TANG_FLOATS);

    const int prep_blocks = (NTILES * NA + 255) / 256;   // 720
    prep_filter_kernel<<<2 * NA + prep_blocks, 256, 0, stream>>>(x, tang, xsT2);
    backproj_kernel<<<NTILES, 256, 0, stream>>>(tang, xsT2, out);
}